// Round 14
// baseline (400.105 us; speedup 1.0000x reference)
//
#include <hip/hip_runtime.h>

#define N_NODES 100000
#define N_EDGES 3200000
#define N_GRAPHS 128

// ---- fixed-capacity radix partition geometry ----
#define RSHIFT 8
#define NPR 256                                   // nodes per range (1<<RSHIFT)
#define R_RANGES ((N_NODES + NPR - 1) / NPR)      // 391
#define CAP 9472                                  // slots per range (mean 8192, +14 sigma)
#define C_CHUNKS 512
#define EPC (N_EDGES / C_CHUNKS)                  // 6250 (exact)
#define SRC_BITS 17                               // N_NODES < 2^17

#define XPB 64                                    // x padded width in bf16 (128 B rows)
#define AXW 48                                    // aggx width

// bf16 helpers (bf16 = top 16 bits of fp32; RNE pack)
__device__ inline unsigned short f2bf(float f) {
    unsigned u = __float_as_uint(f);
    unsigned r = u + 0x7FFFu + ((u >> 16) & 1u);
    return (unsigned short)(r >> 16);
}
__device__ inline float bflo(unsigned u) { return __uint_as_float(u << 16); }
__device__ inline float bfhi(unsigned u) { return __uint_as_float(u & 0xFFFF0000u); }

// ---------------- pad+convert x -> bf16[.,64]; also init range_next ----------------

__global__ __launch_bounds__(256) void padcvt_kernel(const float* __restrict__ x,
                                                     unsigned short* __restrict__ xpb,
                                                     int* __restrict__ range_next) {
    if (blockIdx.x < 2) {
        int i = blockIdx.x * 256 + threadIdx.x;
        if (i < R_RANGES) range_next[i] = i * CAP;
    }
    int idx = blockIdx.x * 256 + threadIdx.x;
    if (idx >= N_NODES * XPB) return;
    int n = idx >> 6;
    int c = idx & 63;
    float v = (c < 47) ? x[n * 47 + c] : 0.f;
    xpb[idx] = f2bf(v);
}

// ---------------- partition v2: LDS counting-sort, coalesced run copy-out ----------------

__global__ __launch_bounds__(256) void partition_kernel(const int* __restrict__ src,
                                                        const int* __restrict__ dst,
                                                        int* __restrict__ range_next,
                                                        int* __restrict__ bucket) {
    __shared__ int sorted[EPC];            // 25 KB
    __shared__ unsigned short rid[EPC];    // 12.5 KB
    __shared__ int cntL[R_RANGES];         // hist -> bump counters
    __shared__ int lstart[R_RANGES];       // local exclusive prefix
    __shared__ int baseL[R_RANGES];        // global claim base
    __shared__ int scanbuf[256];
    const int t = threadIdx.x, b = blockIdx.x;
    const int e0 = b * EPC;
    for (int i = t; i < R_RANGES; i += 256) cntL[i] = 0;
    __syncthreads();
    for (int i = t; i < EPC; i += 256) atomicAdd(&cntL[dst[e0 + i] >> RSHIFT], 1);
    __syncthreads();
    int i0 = 2 * t, i1 = 2 * t + 1;
    int v0 = (i0 < R_RANGES) ? cntL[i0] : 0;
    int v1 = (i1 < R_RANGES) ? cntL[i1] : 0;
    int s = v0 + v1;
    scanbuf[t] = s;
    __syncthreads();
    for (int d = 1; d < 256; d <<= 1) {
        int tv = (t >= d) ? scanbuf[t - d] : 0;
        __syncthreads();
        scanbuf[t] += tv;
        __syncthreads();
    }
    int ex = scanbuf[t] - s;
    if (i0 < R_RANGES) {
        lstart[i0] = ex;
        baseL[i0] = (v0 > 0) ? atomicAdd(&range_next[i0], v0) : 0;
        cntL[i0] = 0;
    }
    if (i1 < R_RANGES) {
        lstart[i1] = ex + v0;
        baseL[i1] = (v1 > 0) ? atomicAdd(&range_next[i1], v1) : 0;
        cntL[i1] = 0;
    }
    __syncthreads();
    for (int i = t; i < EPC; i += 256) {
        int d = dst[e0 + i];
        int sv = src[e0 + i];
        int r = d >> RSHIFT;
        int q = lstart[r] + atomicAdd(&cntL[r], 1);
        sorted[q] = ((d & (NPR - 1)) << SRC_BITS) | sv;
        rid[q] = (unsigned short)r;
    }
    __syncthreads();
    for (int i = t; i < EPC; i += 256) {
        int r = rid[i];
        bucket[baseL[r] + (i - lstart[r])] = sorted[i];
    }
}

// ---------------- build: per-range CSR from LDS-staged segment ----------------

__global__ __launch_bounds__(256) void build_kernel(const int* __restrict__ bucket,
                                                    const int* __restrict__ range_next,
                                                    int* __restrict__ row_ptr,
                                                    int* __restrict__ row_cnt,
                                                    float* __restrict__ dinv,
                                                    int* __restrict__ csr_src) {
    __shared__ int sE[CAP];    // 37.9 KB
    __shared__ int degs[NPR];  // 1 KB
    __shared__ int part[256];
    const int t = threadIdx.x, r = blockIdx.x;
    const int base_node = r * NPR;
    const int seg0 = r * CAP;
    int m = range_next[r] - seg0;
    if (m > CAP) m = CAP;
    for (int i = t; i < m; i += 256) sE[i] = bucket[seg0 + i];
    degs[t] = 0;
    __syncthreads();
    for (int i = t; i < m; i += 256) atomicAdd(&degs[sE[i] >> SRC_BITS], 1);
    __syncthreads();
    int d = degs[t];
    part[t] = d;
    __syncthreads();
    for (int dd = 1; dd < 256; dd <<= 1) {
        int tv = (t >= dd) ? part[t - dd] : 0;
        __syncthreads();
        part[t] += tv;
        __syncthreads();
    }
    int ex = part[t] - d;  // exclusive prefix within range
    int node = base_node + t;
    if (node < N_NODES) {
        row_ptr[node] = seg0 + ex;
        row_cnt[node] = d;
        dinv[node] = rsqrtf((float)(d + 1));  // +1 self loop
    }
    degs[t] = ex;  // repurpose as fill counter
    __syncthreads();
    for (int i = t; i < m; i += 256) {
        int p = sE[i];
        int pos = atomicAdd(&degs[p >> SRC_BITS], 1);
        csr_src[seg0 + pos] = p & ((1 << SRC_BITS) - 1);
    }
}

// ---------------- wprep: csr_w[e] = dinv[csr_src[e]] ----------------

__global__ __launch_bounds__(256) void wprep_kernel(const int* __restrict__ csr_src,
                                                    const int* __restrict__ range_next,
                                                    const float* __restrict__ dinv,
                                                    float* __restrict__ csr_w) {
    const int t = threadIdx.x, r = blockIdx.x;
    const int seg0 = r * CAP;
    int m = range_next[r] - seg0;
    if (m > CAP) m = CAP;
    for (int i = t; i < m; i += 256) {
        csr_w[seg0 + i] = dinv[csr_src[seg0 + i]];
    }
}

// ---------------- Layer-1 aggregation over xpb (bf16), chain-shortened + unroll-2 ----------------

__global__ __launch_bounds__(256) void aggX_kernel(const unsigned short* __restrict__ xpb,
                                                   const float* __restrict__ dinv,
                                                   const int* __restrict__ row_ptr,
                                                   const int* __restrict__ row_cnt,
                                                   const int* __restrict__ csr_src,
                                                   const float* __restrict__ csr_w,
                                                   unsigned short* __restrict__ aggxb) {
    const int tid = threadIdx.x;
    const int n = blockIdx.x * 4 + (tid >> 6);
    if (n >= N_NODES) return;
    const int l = tid & 63;
    const int eo = l >> 3;   // 0..7
    const int cg = l & 7;    // 0..7
    const float dn = dinv[n];

    float acc[8] = {0.f, 0.f, 0.f, 0.f, 0.f, 0.f, 0.f, 0.f};
    if (eo == 0) {  // self loop
        uint4 q = *(const uint4*)(xpb + (size_t)n * XPB + cg * 8);
        float w = dn * dn;
        acc[0] = bflo(q.x) * w; acc[1] = bfhi(q.x) * w;
        acc[2] = bflo(q.y) * w; acc[3] = bfhi(q.y) * w;
        acc[4] = bflo(q.z) * w; acc[5] = bfhi(q.z) * w;
        acc[6] = bflo(q.w) * w; acc[7] = bfhi(q.w) * w;
    }
    const int st = row_ptr[n];
    const int cnt = row_cnt[n];
    int k = eo;
    for (; k + 8 < cnt; k += 16) {
        int s0 = csr_src[st + k];
        int s1 = csr_src[st + k + 8];
        float w0 = csr_w[st + k] * dn;
        float w1 = csr_w[st + k + 8] * dn;
        uint4 q0 = *(const uint4*)(xpb + (size_t)s0 * XPB + cg * 8);
        uint4 q1 = *(const uint4*)(xpb + (size_t)s1 * XPB + cg * 8);
        acc[0] = fmaf(bflo(q0.x), w0, acc[0]); acc[1] = fmaf(bfhi(q0.x), w0, acc[1]);
        acc[2] = fmaf(bflo(q0.y), w0, acc[2]); acc[3] = fmaf(bfhi(q0.y), w0, acc[3]);
        acc[4] = fmaf(bflo(q0.z), w0, acc[4]); acc[5] = fmaf(bfhi(q0.z), w0, acc[5]);
        acc[6] = fmaf(bflo(q0.w), w0, acc[6]); acc[7] = fmaf(bfhi(q0.w), w0, acc[7]);
        acc[0] = fmaf(bflo(q1.x), w1, acc[0]); acc[1] = fmaf(bfhi(q1.x), w1, acc[1]);
        acc[2] = fmaf(bflo(q1.y), w1, acc[2]); acc[3] = fmaf(bfhi(q1.y), w1, acc[3]);
        acc[4] = fmaf(bflo(q1.z), w1, acc[4]); acc[5] = fmaf(bfhi(q1.z), w1, acc[5]);
        acc[6] = fmaf(bflo(q1.w), w1, acc[6]); acc[7] = fmaf(bfhi(q1.w), w1, acc[7]);
    }
    if (k < cnt) {
        int s0 = csr_src[st + k];
        float w0 = csr_w[st + k] * dn;
        uint4 q0 = *(const uint4*)(xpb + (size_t)s0 * XPB + cg * 8);
        acc[0] = fmaf(bflo(q0.x), w0, acc[0]); acc[1] = fmaf(bfhi(q0.x), w0, acc[1]);
        acc[2] = fmaf(bflo(q0.y), w0, acc[2]); acc[3] = fmaf(bfhi(q0.y), w0, acc[3]);
        acc[4] = fmaf(bflo(q0.z), w0, acc[4]); acc[5] = fmaf(bfhi(q0.z), w0, acc[5]);
        acc[6] = fmaf(bflo(q0.w), w0, acc[6]); acc[7] = fmaf(bfhi(q0.w), w0, acc[7]);
    }
#pragma unroll
    for (int off = 8; off <= 32; off <<= 1) {
#pragma unroll
        for (int j = 0; j < 8; ++j) acc[j] += __shfl_xor(acc[j], off);
    }
    if (eo == 0 && cg < 6) {  // cols 0..47
        uint4 o;
        o.x = ((unsigned)f2bf(acc[1]) << 16) | f2bf(acc[0]);
        o.y = ((unsigned)f2bf(acc[3]) << 16) | f2bf(acc[2]);
        o.z = ((unsigned)f2bf(acc[5]) << 16) | f2bf(acc[4]);
        o.w = ((unsigned)f2bf(acc[7]) << 16) | f2bf(acc[6]);
        *(uint4*)(aggxb + (size_t)n * AXW + cg * 8) = o;
    }
}

// ---------------- Fused z = relu(aggx @ W1 + b1) @ W2 — register-resident, zero LDS ----------------
// One thread per node; row[48] and h[64] fully unrolled into VGPRs; weight accesses are
// block-uniform addresses -> scalar (SMEM) loads. No barriers, no bank conflicts.
// R13 bug: row is 48 bf16 = 24 uints (read only 12 -> half the row uninitialized). Fixed.

__global__ __launch_bounds__(128) void fusedgemm_kernel(const unsigned short* __restrict__ aggxb,
                                                        const float* __restrict__ W1,
                                                        const float* __restrict__ b1,
                                                        const float* __restrict__ W2,
                                                        unsigned short* __restrict__ zb) {
    const int n = blockIdx.x * 128 + threadIdx.x;
    if (n >= N_NODES) return;
    // load + unpack the 48-col bf16 row (24 packed uints)
    unsigned qa[24];
    const unsigned* rp = (const unsigned*)(aggxb + (size_t)n * AXW);
#pragma unroll
    for (int i = 0; i < 24; ++i) qa[i] = rp[i];
    float row[48];
#pragma unroll
    for (int i = 0; i < 24; ++i) { row[2 * i] = bflo(qa[i]); row[2 * i + 1] = bfhi(qa[i]); }
    // hidden = relu(row @ W1 + b1)
    float h[64];
#pragma unroll
    for (int c = 0; c < 64; ++c) {
        float s = b1[c];
#pragma unroll
        for (int k = 0; k < 48; ++k) s = fmaf(row[k], W1[k * 64 + c], s);
        h[c] = fmaxf(s, 0.f);
    }
    // z = hidden @ W2, packed bf16 pair writes
    unsigned* op = (unsigned*)(zb + (size_t)n * 32);
#pragma unroll
    for (int cp = 0; cp < 16; ++cp) {
        float s0 = 0.f, s1 = 0.f;
#pragma unroll
        for (int k = 0; k < 64; ++k) {
            s0 = fmaf(h[k], W2[k * 32 + 2 * cp], s0);
            s1 = fmaf(h[k], W2[k * 32 + 2 * cp + 1], s1);
        }
        op[cp] = ((unsigned)f2bf(s1) << 16) | f2bf(s0);
    }
}

// ---------------- Layer-2 aggregation over zb (bf16, 64 B rows, unrolled), +b2, relu ----------------

__global__ __launch_bounds__(256) void aggregate32_kernel(const unsigned short* __restrict__ zb,
                                                          const float* __restrict__ dinv,
                                                          const int* __restrict__ row_ptr,
                                                          const int* __restrict__ row_cnt,
                                                          const int* __restrict__ csr_src,
                                                          const float* __restrict__ csr_w,
                                                          const float* __restrict__ bias,
                                                          float* __restrict__ out) {
    const int tid = threadIdx.x;
    const int n = blockIdx.x * 4 + (tid >> 6);
    if (n >= N_NODES) return;
    const int l = tid & 63;
    const int eo = l >> 2;  // 0..15 edge slot
    const int cg = l & 3;   // 0..3 col group
    const float dn = dinv[n];

    float acc[8] = {0.f, 0.f, 0.f, 0.f, 0.f, 0.f, 0.f, 0.f};
    if (eo == 0) {  // self loop
        uint4 q = *(const uint4*)(zb + (size_t)n * 32 + cg * 8);
        float w = dn * dn;
        acc[0] = bflo(q.x) * w; acc[1] = bfhi(q.x) * w;
        acc[2] = bflo(q.y) * w; acc[3] = bfhi(q.y) * w;
        acc[4] = bflo(q.z) * w; acc[5] = bfhi(q.z) * w;
        acc[6] = bflo(q.w) * w; acc[7] = bfhi(q.w) * w;
    }
    const int st = row_ptr[n];
    const int cnt = row_cnt[n];
    int k = eo;
    for (; k + 16 < cnt; k += 32) {
        int s0 = csr_src[st + k];
        int s1 = csr_src[st + k + 16];
        float w0 = csr_w[st + k] * dn;
        float w1 = csr_w[st + k + 16] * dn;
        uint4 q0 = *(const uint4*)(zb + (size_t)s0 * 32 + cg * 8);
        uint4 q1 = *(const uint4*)(zb + (size_t)s1 * 32 + cg * 8);
        acc[0] = fmaf(bflo(q0.x), w0, acc[0]); acc[1] = fmaf(bfhi(q0.x), w0, acc[1]);
        acc[2] = fmaf(bflo(q0.y), w0, acc[2]); acc[3] = fmaf(bfhi(q0.y), w0, acc[3]);
        acc[4] = fmaf(bflo(q0.z), w0, acc[4]); acc[5] = fmaf(bfhi(q0.z), w0, acc[5]);
        acc[6] = fmaf(bflo(q0.w), w0, acc[6]); acc[7] = fmaf(bfhi(q0.w), w0, acc[7]);
        acc[0] = fmaf(bflo(q1.x), w1, acc[0]); acc[1] = fmaf(bfhi(q1.x), w1, acc[1]);
        acc[2] = fmaf(bflo(q1.y), w1, acc[2]); acc[3] = fmaf(bfhi(q1.y), w1, acc[3]);
        acc[4] = fmaf(bflo(q1.z), w1, acc[4]); acc[5] = fmaf(bfhi(q1.z), w1, acc[5]);
        acc[6] = fmaf(bflo(q1.w), w1, acc[6]); acc[7] = fmaf(bfhi(q1.w), w1, acc[7]);
    }
    if (k < cnt) {
        int s0 = csr_src[st + k];
        float w0 = csr_w[st + k] * dn;
        uint4 q0 = *(const uint4*)(zb + (size_t)s0 * 32 + cg * 8);
        acc[0] = fmaf(bflo(q0.x), w0, acc[0]); acc[1] = fmaf(bfhi(q0.x), w0, acc[1]);
        acc[2] = fmaf(bflo(q0.y), w0, acc[2]); acc[3] = fmaf(bfhi(q0.y), w0, acc[3]);
        acc[4] = fmaf(bflo(q0.z), w0, acc[4]); acc[5] = fmaf(bfhi(q0.z), w0, acc[5]);
        acc[6] = fmaf(bflo(q0.w), w0, acc[6]); acc[7] = fmaf(bfhi(q0.w), w0, acc[7]);
    }
#pragma unroll
    for (int off = 4; off <= 32; off <<= 1) {
#pragma unroll
        for (int j = 0; j < 8; ++j) acc[j] += __shfl_xor(acc[j], off);
    }
    if (eo == 0) {
        const float* bp = bias + cg * 8;
        float4 a, b;
        a.x = fmaxf(acc[0] + bp[0], 0.f);
        a.y = fmaxf(acc[1] + bp[1], 0.f);
        a.z = fmaxf(acc[2] + bp[2], 0.f);
        a.w = fmaxf(acc[3] + bp[3], 0.f);
        b.x = fmaxf(acc[4] + bp[4], 0.f);
        b.y = fmaxf(acc[5] + bp[5], 0.f);
        b.z = fmaxf(acc[6] + bp[6], 0.f);
        b.w = fmaxf(acc[7] + bp[7], 0.f);
        *(float4*)(out + (size_t)n * 32 + cg * 8) = a;
        *(float4*)(out + (size_t)n * 32 + cg * 8 + 4) = b;
    }
}

// ---------------- Pooling (sorted batch, register accumulate, flush on change) ----------------

#define POOL_NPB 256

__global__ __launch_bounds__(256) void pool_kernel(const int* __restrict__ batch,
                                                   const float* __restrict__ h,
                                                   float* __restrict__ g) {
    const int t = threadIdx.x;
    const int c = t & 31;
    const int r = t >> 5;  // 8 node-rows in flight
    int i0 = blockIdx.x * POOL_NPB;
    int i1 = i0 + POOL_NPB;
    if (i1 > N_NODES) i1 = N_NODES;
    int cur_g = -1;
    float acc = 0.f;
    for (int i = i0 + r; i < i1; i += 8) {
        int gi = batch[i];
        float v = h[(size_t)i * 32 + c];
        if (gi != cur_g) {
            if (cur_g >= 0) atomicAdd(&g[cur_g * 32 + c], acc);
            acc = 0.f;
            cur_g = gi;
        }
        acc += v;
    }
    if (cur_g >= 0) atomicAdd(&g[cur_g * 32 + c], acc);
}

// ---------------- MLP head ----------------

__global__ __launch_bounds__(128) void mlp_kernel(const float* __restrict__ g,
                                                  const float* __restrict__ A1, const float* __restrict__ c1,
                                                  const float* __restrict__ A2, const float* __restrict__ c2,
                                                  const float* __restrict__ A3, const float* __restrict__ c3,
                                                  const float* __restrict__ A4, const float* __restrict__ c4,
                                                  float* __restrict__ out) {
    int t = threadIdx.x;  // one thread per graph
    float v[32];
#pragma unroll
    for (int k = 0; k < 32; ++k) v[k] = g[t * 32 + k];
    float u[32];
#pragma unroll
    for (int c = 0; c < 32; ++c) {
        float s = c1[c];
#pragma unroll
        for (int k = 0; k < 32; ++k) s = fmaf(v[k], A1[k * 32 + c], s);
        u[c] = fmaxf(s, 0.f);
    }
    float w[16];
#pragma unroll
    for (int c = 0; c < 16; ++c) {
        float s = c2[c];
#pragma unroll
        for (int k = 0; k < 32; ++k) s = fmaf(u[k], A2[k * 16 + c], s);
        w[c] = fmaxf(s, 0.f);
    }
    float z[8];
#pragma unroll
    for (int c = 0; c < 8; ++c) {
        float s = c3[c];
#pragma unroll
        for (int k = 0; k < 16; ++k) s = fmaf(w[k], A3[k * 8 + c], s);
        z[c] = fmaxf(s, 0.f);
    }
    float s = c4[0];
#pragma unroll
    for (int k = 0; k < 8; ++k) s = fmaf(z[k], A4[k], s);
    out[t] = s;
}

// ---------------- launch ----------------

extern "C" void kernel_launch(void* const* d_in, const int* in_sizes, int n_in,
                              void* d_out, int out_size, void* d_ws, size_t ws_size,
                              hipStream_t stream) {
    const float* x    = (const float*)d_in[0];
    const int*   ei   = (const int*)d_in[1];
    const int*   srcE = ei;             // edge_index[0]
    const int*   dstE = ei + N_EDGES;   // edge_index[1]
    const int*   batch = (const int*)d_in[2];
    const float* W1 = (const float*)d_in[3];  const float* b1 = (const float*)d_in[4];
    const float* W2 = (const float*)d_in[5];  const float* b2 = (const float*)d_in[6];
    const float* A1 = (const float*)d_in[7];  const float* c1 = (const float*)d_in[8];
    const float* A2 = (const float*)d_in[9];  const float* c2 = (const float*)d_in[10];
    const float* A3 = (const float*)d_in[11]; const float* c3 = (const float*)d_in[12];
    const float* A4 = (const float*)d_in[13]; const float* c4 = (const float*)d_in[14];
    float* out = (float*)d_out;

    char* ws = (char*)d_ws;
    size_t off_b = 0;
    auto take = [&](size_t bytes) -> char* {
        char* p = ws + off_b;
        off_b = (off_b + bytes + 255) & ~(size_t)255;
        return p;
    };
    int*            row_ptr    = (int*)take((size_t)N_NODES * 4);
    int*            row_cnt    = (int*)take((size_t)N_NODES * 4);
    float*          dinv       = (float*)take((size_t)N_NODES * 4);
    int*            range_next = (int*)take((size_t)R_RANGES * 4);
    int*            csr_src    = (int*)take((size_t)R_RANGES * CAP * 4);    // 14.8 MB
    float*          csr_w      = (float*)take((size_t)R_RANGES * CAP * 4);  // 14.8 MB
    char*           bz_raw     = take((size_t)R_RANGES * CAP * 4);          // bucket -> zb
    int*            bucket     = (int*)bz_raw;
    unsigned short* zb         = (unsigned short*)bz_raw;                   // bucket dead after build
    unsigned short* xpb        = (unsigned short*)take((size_t)N_NODES * XPB * 2);  // 12.8 MB
    char*           aa_raw     = take((size_t)N_NODES * 32 * 4);            // aggxb (9.6) -> agg (12.8)
    unsigned short* aggxb      = (unsigned short*)aa_raw;
    float*          agg        = (float*)aa_raw;                            // aggxb dead after fusedgemm
    float*          g          = (float*)take((size_t)N_GRAPHS * 32 * 4);
    (void)ws_size; (void)in_sizes; (void)n_in; (void)out_size;

    // ---- pad/convert x (also inits range_next) ----
    padcvt_kernel<<<(N_NODES * XPB + 255) / 256, 256, 0, stream>>>(x, xpb, range_next);

    // ---- CSR build: partition -> per-range build -> edge-weight precompute ----
    partition_kernel<<<C_CHUNKS, 256, 0, stream>>>(srcE, dstE, range_next, bucket);
    build_kernel<<<R_RANGES, 256, 0, stream>>>(bucket, range_next, row_ptr, row_cnt, dinv, csr_src);
    wprep_kernel<<<R_RANGES, 256, 0, stream>>>(csr_src, range_next, dinv, csr_w);

    // ---- GCN layers ----
    aggX_kernel<<<(N_NODES + 3) / 4, 256, 0, stream>>>(xpb, dinv, row_ptr, row_cnt, csr_src, csr_w, aggxb);
    fusedgemm_kernel<<<(N_NODES + 127) / 128, 128, 0, stream>>>(aggxb, W1, b1, W2, zb);
    aggregate32_kernel<<<(N_NODES + 3) / 4, 256, 0, stream>>>(zb, dinv, row_ptr, row_cnt, csr_src, csr_w, b2, agg);

    // ---- pool + head ----
    hipMemsetAsync(g, 0, (size_t)N_GRAPHS * 32 * 4, stream);
    pool_kernel<<<(N_NODES + POOL_NPB - 1) / POOL_NPB, 256, 0, stream>>>(batch, agg, g);
    mlp_kernel<<<1, 128, 0, stream>>>(g, A1, c1, A2, c2, A3, c3, A4, c4, out);
}

// Round 15
// 360.382 us; speedup vs baseline: 1.1102x; 1.1102x over previous
//
#include <hip/hip_runtime.h>

#define N_NODES 100000
#define N_EDGES 3200000
#define N_GRAPHS 128

// ---- fixed-capacity radix partition geometry ----
#define RSHIFT 8
#define NPR 256                                   // nodes per range (1<<RSHIFT)
#define R_RANGES ((N_NODES + NPR - 1) / NPR)      // 391
#define CAP 9472                                  // slots per range (mean 8192, +14 sigma)
#define C_CHUNKS 512
#define EPC (N_EDGES / C_CHUNKS)                  // 6250 (exact)
#define SRC_BITS 17                               // N_NODES < 2^17

#define XPB 64                                    // x padded width in bf16 (128 B rows)
#define AXW 48                                    // aggx width

// bf16 helpers (bf16 = top 16 bits of fp32; RNE pack)
__device__ inline unsigned short f2bf(float f) {
    unsigned u = __float_as_uint(f);
    unsigned r = u + 0x7FFFu + ((u >> 16) & 1u);
    return (unsigned short)(r >> 16);
}
__device__ inline float bflo(unsigned u) { return __uint_as_float(u << 16); }
__device__ inline float bfhi(unsigned u) { return __uint_as_float(u & 0xFFFF0000u); }

// ---------------- pad+convert x -> bf16[.,64]; also init range_next ----------------

__global__ __launch_bounds__(256) void padcvt_kernel(const float* __restrict__ x,
                                                     unsigned short* __restrict__ xpb,
                                                     int* __restrict__ range_next) {
    if (blockIdx.x < 2) {
        int i = blockIdx.x * 256 + threadIdx.x;
        if (i < R_RANGES) range_next[i] = i * CAP;
    }
    int idx = blockIdx.x * 256 + threadIdx.x;
    if (idx >= N_NODES * XPB) return;
    int n = idx >> 6;
    int c = idx & 63;
    float v = (c < 47) ? x[n * 47 + c] : 0.f;
    xpb[idx] = f2bf(v);
}

// ---------------- partition v2: LDS counting-sort, coalesced run copy-out ----------------

__global__ __launch_bounds__(256) void partition_kernel(const int* __restrict__ src,
                                                        const int* __restrict__ dst,
                                                        int* __restrict__ range_next,
                                                        int* __restrict__ bucket) {
    __shared__ int sorted[EPC];            // 25 KB
    __shared__ unsigned short rid[EPC];    // 12.5 KB
    __shared__ int cntL[R_RANGES];         // hist -> bump counters
    __shared__ int lstart[R_RANGES];       // local exclusive prefix
    __shared__ int baseL[R_RANGES];        // global claim base
    __shared__ int scanbuf[256];
    const int t = threadIdx.x, b = blockIdx.x;
    const int e0 = b * EPC;
    for (int i = t; i < R_RANGES; i += 256) cntL[i] = 0;
    __syncthreads();
    for (int i = t; i < EPC; i += 256) atomicAdd(&cntL[dst[e0 + i] >> RSHIFT], 1);
    __syncthreads();
    int i0 = 2 * t, i1 = 2 * t + 1;
    int v0 = (i0 < R_RANGES) ? cntL[i0] : 0;
    int v1 = (i1 < R_RANGES) ? cntL[i1] : 0;
    int s = v0 + v1;
    scanbuf[t] = s;
    __syncthreads();
    for (int d = 1; d < 256; d <<= 1) {
        int tv = (t >= d) ? scanbuf[t - d] : 0;
        __syncthreads();
        scanbuf[t] += tv;
        __syncthreads();
    }
    int ex = scanbuf[t] - s;
    if (i0 < R_RANGES) {
        lstart[i0] = ex;
        baseL[i0] = (v0 > 0) ? atomicAdd(&range_next[i0], v0) : 0;
        cntL[i0] = 0;
    }
    if (i1 < R_RANGES) {
        lstart[i1] = ex + v0;
        baseL[i1] = (v1 > 0) ? atomicAdd(&range_next[i1], v1) : 0;
        cntL[i1] = 0;
    }
    __syncthreads();
    for (int i = t; i < EPC; i += 256) {
        int d = dst[e0 + i];
        int sv = src[e0 + i];
        int r = d >> RSHIFT;
        int q = lstart[r] + atomicAdd(&cntL[r], 1);
        sorted[q] = ((d & (NPR - 1)) << SRC_BITS) | sv;
        rid[q] = (unsigned short)r;
    }
    __syncthreads();
    for (int i = t; i < EPC; i += 256) {
        int r = rid[i];
        bucket[baseL[r] + (i - lstart[r])] = sorted[i];
    }
}

// ---------------- build: per-range CSR from LDS-staged segment ----------------

__global__ __launch_bounds__(256) void build_kernel(const int* __restrict__ bucket,
                                                    const int* __restrict__ range_next,
                                                    int* __restrict__ row_ptr,
                                                    int* __restrict__ row_cnt,
                                                    float* __restrict__ dinv,
                                                    int* __restrict__ csr_src) {
    __shared__ int sE[CAP];    // 37.9 KB
    __shared__ int degs[NPR];  // 1 KB
    __shared__ int part[256];
    const int t = threadIdx.x, r = blockIdx.x;
    const int base_node = r * NPR;
    const int seg0 = r * CAP;
    int m = range_next[r] - seg0;
    if (m > CAP) m = CAP;
    for (int i = t; i < m; i += 256) sE[i] = bucket[seg0 + i];
    degs[t] = 0;
    __syncthreads();
    for (int i = t; i < m; i += 256) atomicAdd(&degs[sE[i] >> SRC_BITS], 1);
    __syncthreads();
    int d = degs[t];
    part[t] = d;
    __syncthreads();
    for (int dd = 1; dd < 256; dd <<= 1) {
        int tv = (t >= dd) ? part[t - dd] : 0;
        __syncthreads();
        part[t] += tv;
        __syncthreads();
    }
    int ex = part[t] - d;  // exclusive prefix within range
    int node = base_node + t;
    if (node < N_NODES) {
        row_ptr[node] = seg0 + ex;
        row_cnt[node] = d;
        dinv[node] = rsqrtf((float)(d + 1));  // +1 self loop
    }
    degs[t] = ex;  // repurpose as fill counter
    __syncthreads();
    for (int i = t; i < m; i += 256) {
        int p = sE[i];
        int pos = atomicAdd(&degs[p >> SRC_BITS], 1);
        csr_src[seg0 + pos] = p & ((1 << SRC_BITS) - 1);
    }
}

// ---------------- wprep: csr_w[e] = dinv[csr_src[e]] ----------------

__global__ __launch_bounds__(256) void wprep_kernel(const int* __restrict__ csr_src,
                                                    const int* __restrict__ range_next,
                                                    const float* __restrict__ dinv,
                                                    float* __restrict__ csr_w) {
    const int t = threadIdx.x, r = blockIdx.x;
    const int seg0 = r * CAP;
    int m = range_next[r] - seg0;
    if (m > CAP) m = CAP;
    for (int i = t; i < m; i += 256) {
        csr_w[seg0 + i] = dinv[csr_src[seg0 + i]];
    }
}

// ---------------- Layer-1 aggregation over xpb (bf16), chain-shortened + unroll-2 ----------------

__global__ __launch_bounds__(256) void aggX_kernel(const unsigned short* __restrict__ xpb,
                                                   const float* __restrict__ dinv,
                                                   const int* __restrict__ row_ptr,
                                                   const int* __restrict__ row_cnt,
                                                   const int* __restrict__ csr_src,
                                                   const float* __restrict__ csr_w,
                                                   unsigned short* __restrict__ aggxb) {
    const int tid = threadIdx.x;
    const int n = blockIdx.x * 4 + (tid >> 6);
    if (n >= N_NODES) return;
    const int l = tid & 63;
    const int eo = l >> 3;   // 0..7
    const int cg = l & 7;    // 0..7
    const float dn = dinv[n];

    float acc[8] = {0.f, 0.f, 0.f, 0.f, 0.f, 0.f, 0.f, 0.f};
    if (eo == 0) {  // self loop
        uint4 q = *(const uint4*)(xpb + (size_t)n * XPB + cg * 8);
        float w = dn * dn;
        acc[0] = bflo(q.x) * w; acc[1] = bfhi(q.x) * w;
        acc[2] = bflo(q.y) * w; acc[3] = bfhi(q.y) * w;
        acc[4] = bflo(q.z) * w; acc[5] = bfhi(q.z) * w;
        acc[6] = bflo(q.w) * w; acc[7] = bfhi(q.w) * w;
    }
    const int st = row_ptr[n];
    const int cnt = row_cnt[n];
    int k = eo;
    for (; k + 8 < cnt; k += 16) {
        int s0 = csr_src[st + k];
        int s1 = csr_src[st + k + 8];
        float w0 = csr_w[st + k] * dn;
        float w1 = csr_w[st + k + 8] * dn;
        uint4 q0 = *(const uint4*)(xpb + (size_t)s0 * XPB + cg * 8);
        uint4 q1 = *(const uint4*)(xpb + (size_t)s1 * XPB + cg * 8);
        acc[0] = fmaf(bflo(q0.x), w0, acc[0]); acc[1] = fmaf(bfhi(q0.x), w0, acc[1]);
        acc[2] = fmaf(bflo(q0.y), w0, acc[2]); acc[3] = fmaf(bfhi(q0.y), w0, acc[3]);
        acc[4] = fmaf(bflo(q0.z), w0, acc[4]); acc[5] = fmaf(bfhi(q0.z), w0, acc[5]);
        acc[6] = fmaf(bflo(q0.w), w0, acc[6]); acc[7] = fmaf(bfhi(q0.w), w0, acc[7]);
        acc[0] = fmaf(bflo(q1.x), w1, acc[0]); acc[1] = fmaf(bfhi(q1.x), w1, acc[1]);
        acc[2] = fmaf(bflo(q1.y), w1, acc[2]); acc[3] = fmaf(bfhi(q1.y), w1, acc[3]);
        acc[4] = fmaf(bflo(q1.z), w1, acc[4]); acc[5] = fmaf(bfhi(q1.z), w1, acc[5]);
        acc[6] = fmaf(bflo(q1.w), w1, acc[6]); acc[7] = fmaf(bfhi(q1.w), w1, acc[7]);
    }
    if (k < cnt) {
        int s0 = csr_src[st + k];
        float w0 = csr_w[st + k] * dn;
        uint4 q0 = *(const uint4*)(xpb + (size_t)s0 * XPB + cg * 8);
        acc[0] = fmaf(bflo(q0.x), w0, acc[0]); acc[1] = fmaf(bfhi(q0.x), w0, acc[1]);
        acc[2] = fmaf(bflo(q0.y), w0, acc[2]); acc[3] = fmaf(bfhi(q0.y), w0, acc[3]);
        acc[4] = fmaf(bflo(q0.z), w0, acc[4]); acc[5] = fmaf(bfhi(q0.z), w0, acc[5]);
        acc[6] = fmaf(bflo(q0.w), w0, acc[6]); acc[7] = fmaf(bfhi(q0.w), w0, acc[7]);
    }
#pragma unroll
    for (int off = 8; off <= 32; off <<= 1) {
#pragma unroll
        for (int j = 0; j < 8; ++j) acc[j] += __shfl_xor(acc[j], off);
    }
    if (eo == 0 && cg < 6) {  // cols 0..47
        uint4 o;
        o.x = ((unsigned)f2bf(acc[1]) << 16) | f2bf(acc[0]);
        o.y = ((unsigned)f2bf(acc[3]) << 16) | f2bf(acc[2]);
        o.z = ((unsigned)f2bf(acc[5]) << 16) | f2bf(acc[4]);
        o.w = ((unsigned)f2bf(acc[7]) << 16) | f2bf(acc[6]);
        *(uint4*)(aggxb + (size_t)n * AXW + cg * 8) = o;
    }
}

// ---------------- Fused z = relu(aggx @ W1 + b1) @ W2 — LDS, row-major weights, wide reads ----------------
// 16 nodes per pass, 5 passes (80 nodes/block, grid 1250 exact).
// Phase 1: thread = (node nn: t>>4, colgroup cg: t&15) -> 4 cols via one ds_read_b128 of W1s
//   (row-major W1s[k*64+c]: 16 float4/wave-group, conflict-free; rows[nn][k] is 16-way broadcast).
// Phase 2: 2 cols via float2 of W2s. LDS instr per node: 160 (R10) -> 56.

#define FG_NPB 80

__global__ __launch_bounds__(256) void fusedgemm_kernel(const unsigned short* __restrict__ aggxb,
                                                        const float* __restrict__ W1,
                                                        const float* __restrict__ b1,
                                                        const float* __restrict__ W2,
                                                        unsigned short* __restrict__ zb) {
    __shared__ float W1s[AXW * 64];   // 12 KB, row 47 zeroed
    __shared__ float W2s[64 * 32];    // 8 KB
    __shared__ float b1s[64];
    __shared__ float rows[16][48];    // 3 KB
    __shared__ float ts[16][64];      // 4 KB
    const int t = threadIdx.x;
    for (int i = t; i < 47 * 64; i += 256) W1s[i] = W1[i];
    if (t < 64) { W1s[47 * 64 + t] = 0.f; b1s[t] = b1[t]; }
    for (int i = t; i < 64 * 32; i += 256) W2s[i] = W2[i];

    const int nn = t >> 4;   // 0..15 node-in-pass
    const int cg = t & 15;   // 0..15 col group
    const int base = blockIdx.x * FG_NPB;

    for (int pass = 0; pass < FG_NPB / 16; ++pass) {
        const int nb = base + pass * 16;
        // stage 16 rows (16 x 24 packed uints)
        for (int i = t; i < 16 * 24; i += 256) {
            int node = i / 24, p = i - node * 24;
            unsigned q = ((const unsigned*)(aggxb + (size_t)(nb + node) * AXW))[p];
            rows[node][2 * p] = bflo(q);
            rows[node][2 * p + 1] = bfhi(q);
        }
        __syncthreads();
        // phase 1: hidden = relu(rows @ W1 + b1); 4 cols/thread via float4 weight reads
        {
            float4 acc = *(const float4*)&b1s[cg * 4];
#pragma unroll
            for (int k = 0; k < 48; ++k) {
                float rv = rows[nn][k];
                float4 wv = *(const float4*)&W1s[k * 64 + cg * 4];
                acc.x = fmaf(rv, wv.x, acc.x);
                acc.y = fmaf(rv, wv.y, acc.y);
                acc.z = fmaf(rv, wv.z, acc.z);
                acc.w = fmaf(rv, wv.w, acc.w);
            }
            float4 hv;
            hv.x = fmaxf(acc.x, 0.f); hv.y = fmaxf(acc.y, 0.f);
            hv.z = fmaxf(acc.z, 0.f); hv.w = fmaxf(acc.w, 0.f);
            *(float4*)&ts[nn][cg * 4] = hv;
        }
        __syncthreads();
        // phase 2: z = hidden @ W2; 2 cols/thread via float2 weight reads
        {
            float s0 = 0.f, s1 = 0.f;
#pragma unroll
            for (int k = 0; k < 64; ++k) {
                float tv = ts[nn][k];
                float2 wv = *(const float2*)&W2s[k * 32 + cg * 2];
                s0 = fmaf(tv, wv.x, s0);
                s1 = fmaf(tv, wv.y, s1);
            }
            ((unsigned*)zb)[(size_t)(nb + nn) * 16 + cg] =
                ((unsigned)f2bf(s1) << 16) | f2bf(s0);
        }
        __syncthreads();
    }
}

// ---------------- Layer-2 aggregation over zb (bf16, 64 B rows, unrolled), +b2, relu ----------------

__global__ __launch_bounds__(256) void aggregate32_kernel(const unsigned short* __restrict__ zb,
                                                          const float* __restrict__ dinv,
                                                          const int* __restrict__ row_ptr,
                                                          const int* __restrict__ row_cnt,
                                                          const int* __restrict__ csr_src,
                                                          const float* __restrict__ csr_w,
                                                          const float* __restrict__ bias,
                                                          float* __restrict__ out) {
    const int tid = threadIdx.x;
    const int n = blockIdx.x * 4 + (tid >> 6);
    if (n >= N_NODES) return;
    const int l = tid & 63;
    const int eo = l >> 2;  // 0..15 edge slot
    const int cg = l & 3;   // 0..3 col group
    const float dn = dinv[n];

    float acc[8] = {0.f, 0.f, 0.f, 0.f, 0.f, 0.f, 0.f, 0.f};
    if (eo == 0) {  // self loop
        uint4 q = *(const uint4*)(zb + (size_t)n * 32 + cg * 8);
        float w = dn * dn;
        acc[0] = bflo(q.x) * w; acc[1] = bfhi(q.x) * w;
        acc[2] = bflo(q.y) * w; acc[3] = bfhi(q.y) * w;
        acc[4] = bflo(q.z) * w; acc[5] = bfhi(q.z) * w;
        acc[6] = bflo(q.w) * w; acc[7] = bfhi(q.w) * w;
    }
    const int st = row_ptr[n];
    const int cnt = row_cnt[n];
    int k = eo;
    for (; k + 16 < cnt; k += 32) {
        int s0 = csr_src[st + k];
        int s1 = csr_src[st + k + 16];
        float w0 = csr_w[st + k] * dn;
        float w1 = csr_w[st + k + 16] * dn;
        uint4 q0 = *(const uint4*)(zb + (size_t)s0 * 32 + cg * 8);
        uint4 q1 = *(const uint4*)(zb + (size_t)s1 * 32 + cg * 8);
        acc[0] = fmaf(bflo(q0.x), w0, acc[0]); acc[1] = fmaf(bfhi(q0.x), w0, acc[1]);
        acc[2] = fmaf(bflo(q0.y), w0, acc[2]); acc[3] = fmaf(bfhi(q0.y), w0, acc[3]);
        acc[4] = fmaf(bflo(q0.z), w0, acc[4]); acc[5] = fmaf(bfhi(q0.z), w0, acc[5]);
        acc[6] = fmaf(bflo(q0.w), w0, acc[6]); acc[7] = fmaf(bfhi(q0.w), w0, acc[7]);
        acc[0] = fmaf(bflo(q1.x), w1, acc[0]); acc[1] = fmaf(bfhi(q1.x), w1, acc[1]);
        acc[2] = fmaf(bflo(q1.y), w1, acc[2]); acc[3] = fmaf(bfhi(q1.y), w1, acc[3]);
        acc[4] = fmaf(bflo(q1.z), w1, acc[4]); acc[5] = fmaf(bfhi(q1.z), w1, acc[5]);
        acc[6] = fmaf(bflo(q1.w), w1, acc[6]); acc[7] = fmaf(bfhi(q1.w), w1, acc[7]);
    }
    if (k < cnt) {
        int s0 = csr_src[st + k];
        float w0 = csr_w[st + k] * dn;
        uint4 q0 = *(const uint4*)(zb + (size_t)s0 * 32 + cg * 8);
        acc[0] = fmaf(bflo(q0.x), w0, acc[0]); acc[1] = fmaf(bfhi(q0.x), w0, acc[1]);
        acc[2] = fmaf(bflo(q0.y), w0, acc[2]); acc[3] = fmaf(bfhi(q0.y), w0, acc[3]);
        acc[4] = fmaf(bflo(q0.z), w0, acc[4]); acc[5] = fmaf(bfhi(q0.z), w0, acc[5]);
        acc[6] = fmaf(bflo(q0.w), w0, acc[6]); acc[7] = fmaf(bfhi(q0.w), w0, acc[7]);
    }
#pragma unroll
    for (int off = 4; off <= 32; off <<= 1) {
#pragma unroll
        for (int j = 0; j < 8; ++j) acc[j] += __shfl_xor(acc[j], off);
    }
    if (eo == 0) {
        const float* bp = bias + cg * 8;
        float4 a, b;
        a.x = fmaxf(acc[0] + bp[0], 0.f);
        a.y = fmaxf(acc[1] + bp[1], 0.f);
        a.z = fmaxf(acc[2] + bp[2], 0.f);
        a.w = fmaxf(acc[3] + bp[3], 0.f);
        b.x = fmaxf(acc[4] + bp[4], 0.f);
        b.y = fmaxf(acc[5] + bp[5], 0.f);
        b.z = fmaxf(acc[6] + bp[6], 0.f);
        b.w = fmaxf(acc[7] + bp[7], 0.f);
        *(float4*)(out + (size_t)n * 32 + cg * 8) = a;
        *(float4*)(out + (size_t)n * 32 + cg * 8 + 4) = b;
    }
}

// ---------------- Pooling (sorted batch, register accumulate, flush on change) ----------------

#define POOL_NPB 256

__global__ __launch_bounds__(256) void pool_kernel(const int* __restrict__ batch,
                                                   const float* __restrict__ h,
                                                   float* __restrict__ g) {
    const int t = threadIdx.x;
    const int c = t & 31;
    const int r = t >> 5;  // 8 node-rows in flight
    int i0 = blockIdx.x * POOL_NPB;
    int i1 = i0 + POOL_NPB;
    if (i1 > N_NODES) i1 = N_NODES;
    int cur_g = -1;
    float acc = 0.f;
    for (int i = i0 + r; i < i1; i += 8) {
        int gi = batch[i];
        float v = h[(size_t)i * 32 + c];
        if (gi != cur_g) {
            if (cur_g >= 0) atomicAdd(&g[cur_g * 32 + c], acc);
            acc = 0.f;
            cur_g = gi;
        }
        acc += v;
    }
    if (cur_g >= 0) atomicAdd(&g[cur_g * 32 + c], acc);
}

// ---------------- MLP head ----------------

__global__ __launch_bounds__(128) void mlp_kernel(const float* __restrict__ g,
                                                  const float* __restrict__ A1, const float* __restrict__ c1,
                                                  const float* __restrict__ A2, const float* __restrict__ c2,
                                                  const float* __restrict__ A3, const float* __restrict__ c3,
                                                  const float* __restrict__ A4, const float* __restrict__ c4,
                                                  float* __restrict__ out) {
    int t = threadIdx.x;  // one thread per graph
    float v[32];
#pragma unroll
    for (int k = 0; k < 32; ++k) v[k] = g[t * 32 + k];
    float u[32];
#pragma unroll
    for (int c = 0; c < 32; ++c) {
        float s = c1[c];
#pragma unroll
        for (int k = 0; k < 32; ++k) s = fmaf(v[k], A1[k * 32 + c], s);
        u[c] = fmaxf(s, 0.f);
    }
    float w[16];
#pragma unroll
    for (int c = 0; c < 16; ++c) {
        float s = c2[c];
#pragma unroll
        for (int k = 0; k < 32; ++k) s = fmaf(u[k], A2[k * 16 + c], s);
        w[c] = fmaxf(s, 0.f);
    }
    float z[8];
#pragma unroll
    for (int c = 0; c < 8; ++c) {
        float s = c3[c];
#pragma unroll
        for (int k = 0; k < 16; ++k) s = fmaf(w[k], A3[k * 8 + c], s);
        z[c] = fmaxf(s, 0.f);
    }
    float s = c4[0];
#pragma unroll
    for (int k = 0; k < 8; ++k) s = fmaf(z[k], A4[k], s);
    out[t] = s;
}

// ---------------- launch ----------------

extern "C" void kernel_launch(void* const* d_in, const int* in_sizes, int n_in,
                              void* d_out, int out_size, void* d_ws, size_t ws_size,
                              hipStream_t stream) {
    const float* x    = (const float*)d_in[0];
    const int*   ei   = (const int*)d_in[1];
    const int*   srcE = ei;             // edge_index[0]
    const int*   dstE = ei + N_EDGES;   // edge_index[1]
    const int*   batch = (const int*)d_in[2];
    const float* W1 = (const float*)d_in[3];  const float* b1 = (const float*)d_in[4];
    const float* W2 = (const float*)d_in[5];  const float* b2 = (const float*)d_in[6];
    const float* A1 = (const float*)d_in[7];  const float* c1 = (const float*)d_in[8];
    const float* A2 = (const float*)d_in[9];  const float* c2 = (const float*)d_in[10];
    const float* A3 = (const float*)d_in[11]; const float* c3 = (const float*)d_in[12];
    const float* A4 = (const float*)d_in[13]; const float* c4 = (const float*)d_in[14];
    float* out = (float*)d_out;

    char* ws = (char*)d_ws;
    size_t off_b = 0;
    auto take = [&](size_t bytes) -> char* {
        char* p = ws + off_b;
        off_b = (off_b + bytes + 255) & ~(size_t)255;
        return p;
    };
    int*            row_ptr    = (int*)take((size_t)N_NODES * 4);
    int*            row_cnt    = (int*)take((size_t)N_NODES * 4);
    float*          dinv       = (float*)take((size_t)N_NODES * 4);
    int*            range_next = (int*)take((size_t)R_RANGES * 4);
    int*            csr_src    = (int*)take((size_t)R_RANGES * CAP * 4);    // 14.8 MB
    float*          csr_w      = (float*)take((size_t)R_RANGES * CAP * 4);  // 14.8 MB
    char*           bz_raw     = take((size_t)R_RANGES * CAP * 4);          // bucket -> zb
    int*            bucket     = (int*)bz_raw;
    unsigned short* zb         = (unsigned short*)bz_raw;                   // bucket dead after build
    unsigned short* xpb        = (unsigned short*)take((size_t)N_NODES * XPB * 2);  // 12.8 MB
    char*           aa_raw     = take((size_t)N_NODES * 32 * 4);            // aggxb (9.6) -> agg (12.8)
    unsigned short* aggxb      = (unsigned short*)aa_raw;
    float*          agg        = (float*)aa_raw;                            // aggxb dead after fusedgemm
    float*          g          = (float*)take((size_t)N_GRAPHS * 32 * 4);
    (void)ws_size; (void)in_sizes; (void)n_in; (void)out_size;

    // ---- pad/convert x (also inits range_next) ----
    padcvt_kernel<<<(N_NODES * XPB + 255) / 256, 256, 0, stream>>>(x, xpb, range_next);

    // ---- CSR build: partition -> per-range build -> edge-weight precompute ----
    partition_kernel<<<C_CHUNKS, 256, 0, stream>>>(srcE, dstE, range_next, bucket);
    build_kernel<<<R_RANGES, 256, 0, stream>>>(bucket, range_next, row_ptr, row_cnt, dinv, csr_src);
    wprep_kernel<<<R_RANGES, 256, 0, stream>>>(csr_src, range_next, dinv, csr_w);

    // ---- GCN layers ----
    aggX_kernel<<<(N_NODES + 3) / 4, 256, 0, stream>>>(xpb, dinv, row_ptr, row_cnt, csr_src, csr_w, aggxb);
    fusedgemm_kernel<<<N_NODES / FG_NPB, 256, 0, stream>>>(aggxb, W1, b1, W2, zb);
    aggregate32_kernel<<<(N_NODES + 3) / 4, 256, 0, stream>>>(zb, dinv, row_ptr, row_cnt, csr_src, csr_w, b2, agg);

    // ---- pool + head ----
    hipMemsetAsync(g, 0, (size_t)N_GRAPHS * 32 * 4, stream);
    pool_kernel<<<(N_NODES + POOL_NPB - 1) / POOL_NPB, 256, 0, stream>>>(batch, agg, g);
    mlp_kernel<<<1, 128, 0, stream>>>(g, A1, c1, A2, c2, A3, c3, A4, c4, out);
}